// Round 1
// baseline (180.635 us; speedup 1.0000x reference)
//
#include <hip/hip_runtime.h>
#include <hip/hip_bf16.h>
#include <float.h>

#define N_SAMP   1024
#define C_IN     22
#define HW       361
#define C_TRUNK  384
#define HID      128
#define NHIST    5
#define HIST_START 9
#define NGATE    512   // 4*HID

// ---------------- Kernel 1: argmax + sum + gather (with reversal/masking) ----
__global__ __launch_bounds__(256) void prep_kernel(
    const float* __restrict__ inp,      // (N, 22, 361)
    const float* __restrict__ trunk,    // (N, 384, 361)
    float* __restrict__ seq)            // (N, 5, 384)  already reversed+masked
{
  const int n   = blockIdx.x;
  const int tid = threadIdx.x;
  __shared__ float sv[256];
  __shared__ int   si[256];
  __shared__ float ss[256];
  __shared__ int   plane_idx[NHIST];
  __shared__ float plane_move[NHIST];

  for (int t = 0; t < NHIST; ++t) {
    const float* base = inp + ((size_t)n * C_IN + HIST_START + t) * HW;
    float v = -FLT_MAX; int vi = 0x7fffffff; float sum = 0.f;
    for (int i = tid; i < HW; i += 256) {
      float x = base[i];
      sum += x;
      if (x > v) { v = x; vi = i; }   // strict > keeps first occurrence in-thread
    }
    sv[tid] = v; si[tid] = vi; ss[tid] = sum;
    __syncthreads();
    for (int off = 128; off > 0; off >>= 1) {
      if (tid < off) {
        float v2 = sv[tid + off]; int i2 = si[tid + off];
        if (v2 > sv[tid] || (v2 == sv[tid] && i2 < si[tid])) { sv[tid] = v2; si[tid] = i2; }
        ss[tid] += ss[tid + off];
      }
      __syncthreads();
    }
    if (tid == 0) {
      plane_idx[t]  = si[0];
      plane_move[t] = (ss[0] > 0.5f) ? 1.f : 0.f;
    }
    __syncthreads();
  }

  // gather: seq[n][t][c] = move[4-t] * trunk[n][c][idx[4-t]]
  for (int e = tid; e < NHIST * C_TRUNK; e += 256) {
    int t = e / C_TRUNK;
    int c = e - t * C_TRUNK;
    int rawt = NHIST - 1 - t;
    int p    = plane_idx[rawt];
    float m  = plane_move[rawt];
    seq[((size_t)n * NHIST + t) * C_TRUNK + c] =
        m * trunk[((size_t)n * C_TRUNK + c) * HW + p];
  }
}

// ---------------- Kernel 2: G = seq @ w_ih^T + b_ih + b_hh --------------------
// M=5120, N=512, K=384.  BM=BN=64, BK=16, 256 threads, 4x4 microtile.
#define BM 64
#define BN 64
#define BK 16

__global__ __launch_bounds__(256) void gates_kernel(
    const float* __restrict__ seq,   // (5120, 384)
    const float* __restrict__ w_ih,  // (512, 384)
    const float* __restrict__ b_ih,  // (512)
    const float* __restrict__ b_hh,  // (512)
    float* __restrict__ G)           // (5120, 512)
{
  __shared__ float As[BK][BM];
  __shared__ float Bs[BK][BN];
  const int tid = threadIdx.x;
  const int m0  = blockIdx.y * BM;
  const int j0  = blockIdx.x * BN;
  const int ty  = tid >> 4;        // 0..15
  const int tx  = tid & 15;        // 0..15

  float acc[4][4];
  #pragma unroll
  for (int i = 0; i < 4; ++i)
    #pragma unroll
    for (int j = 0; j < 4; ++j) acc[i][j] = 0.f;

  const int lm = tid >> 2;          // 0..63  (row within tile)
  const int lk = (tid & 3) * 4;     // 0,4,8,12 (k within tile)

  for (int k0 = 0; k0 < C_TRUNK; k0 += BK) {
    float4 a = *(const float4*)(seq  + (size_t)(m0 + lm) * C_TRUNK + k0 + lk);
    float4 b = *(const float4*)(w_ih + (size_t)(j0 + lm) * C_TRUNK + k0 + lk);
    As[lk+0][lm] = a.x; As[lk+1][lm] = a.y; As[lk+2][lm] = a.z; As[lk+3][lm] = a.w;
    Bs[lk+0][lm] = b.x; Bs[lk+1][lm] = b.y; Bs[lk+2][lm] = b.z; Bs[lk+3][lm] = b.w;
    __syncthreads();
    #pragma unroll
    for (int k = 0; k < BK; ++k) {
      float4 av = *(const float4*)&As[k][ty * 4];
      float4 bv = *(const float4*)&Bs[k][tx * 4];
      float aa[4] = {av.x, av.y, av.z, av.w};
      float bb[4] = {bv.x, bv.y, bv.z, bv.w};
      #pragma unroll
      for (int i = 0; i < 4; ++i)
        #pragma unroll
        for (int j = 0; j < 4; ++j) acc[i][j] += aa[i] * bb[j];
    }
    __syncthreads();
  }

  #pragma unroll
  for (int i = 0; i < 4; ++i) {
    int m = m0 + ty * 4 + i;
    #pragma unroll
    for (int j = 0; j < 4; ++j) {
      int col = j0 + tx * 4 + j;
      G[(size_t)m * NGATE + col] = acc[i][j] + b_ih[col] + b_hh[col];
    }
  }
}

// ---------------- Kernel 3: recurrence + projection ---------------------------
// 4 samples per block of 128 threads; thread j owns hidden unit j.
__global__ __launch_bounds__(128) void lstm_kernel(
    const float* __restrict__ G,       // (1024, 5, 512)
    const float* __restrict__ w_hh,    // (512, 128)
    const float* __restrict__ w_proj,  // (384, 128)
    const float* __restrict__ b_proj,  // (384)
    float* __restrict__ out)           // (1024, 384)
{
  const int n0  = blockIdx.x * 4;
  const int tid = threadIdx.x;          // 0..127
  __shared__ float hs[4][HID];
  float c_reg[4] = {0.f, 0.f, 0.f, 0.f};
  #pragma unroll
  for (int s = 0; s < 4; ++s) hs[s][tid] = 0.f;
  __syncthreads();

  const float4* wr0 = (const float4*)(w_hh + (size_t)(0 * HID + tid) * HID);
  const float4* wr1 = (const float4*)(w_hh + (size_t)(1 * HID + tid) * HID);
  const float4* wr2 = (const float4*)(w_hh + (size_t)(2 * HID + tid) * HID);
  const float4* wr3 = (const float4*)(w_hh + (size_t)(3 * HID + tid) * HID);

  for (int t = 0; t < NHIST; ++t) {
    float acc[4][4];   // [gate][sample]
    #pragma unroll
    for (int s = 0; s < 4; ++s) {
      const float* gp = G + ((size_t)(n0 + s) * NHIST + t) * NGATE + tid;
      acc[0][s] = gp[0];
      acc[1][s] = gp[HID];
      acc[2][s] = gp[2 * HID];
      acc[3][s] = gp[3 * HID];
    }
    #pragma unroll 8
    for (int k4 = 0; k4 < HID / 4; ++k4) {
      float4 w0 = wr0[k4], w1 = wr1[k4], w2 = wr2[k4], w3 = wr3[k4];
      #pragma unroll
      for (int s = 0; s < 4; ++s) {
        float4 hv = *(const float4*)&hs[s][k4 * 4];
        acc[0][s] += w0.x*hv.x + w0.y*hv.y + w0.z*hv.z + w0.w*hv.w;
        acc[1][s] += w1.x*hv.x + w1.y*hv.y + w1.z*hv.z + w1.w*hv.w;
        acc[2][s] += w2.x*hv.x + w2.y*hv.y + w2.z*hv.z + w2.w*hv.w;
        acc[3][s] += w3.x*hv.x + w3.y*hv.y + w3.z*hv.z + w3.w*hv.w;
      }
    }
    __syncthreads();   // all reads of old h done
    #pragma unroll
    for (int s = 0; s < 4; ++s) {
      float ig = 1.f / (1.f + __expf(-acc[0][s]));
      float fg = 1.f / (1.f + __expf(-acc[1][s]));
      float gg = tanhf(acc[2][s]);
      float og = 1.f / (1.f + __expf(-acc[3][s]));
      c_reg[s] = fg * c_reg[s] + ig * gg;
      hs[s][tid] = og * tanhf(c_reg[s]);
    }
    __syncthreads();   // new h visible
  }

  // projection: out[n][cc] = h_final . w_proj[cc] + b_proj[cc]
  for (int e = tid; e < 4 * C_TRUNK; e += 128) {
    int s  = e / C_TRUNK;
    int cc = e - s * C_TRUNK;
    const float4* wp = (const float4*)(w_proj + (size_t)cc * HID);
    float a = b_proj[cc];
    #pragma unroll 8
    for (int k4 = 0; k4 < HID / 4; ++k4) {
      float4 w  = wp[k4];
      float4 hv = *(const float4*)&hs[s][k4 * 4];
      a += w.x*hv.x + w.y*hv.y + w.z*hv.z + w.w*hv.w;
    }
    out[(size_t)(n0 + s) * C_TRUNK + cc] = a;
  }
}

extern "C" void kernel_launch(void* const* d_in, const int* in_sizes, int n_in,
                              void* d_out, int out_size, void* d_ws, size_t ws_size,
                              hipStream_t stream) {
  const float* inp    = (const float*)d_in[0];  // input_spatial (1024,22,19,19)
  const float* trunk  = (const float*)d_in[1];  // trunk_out     (1024,384,19,19)
  const float* w_ih   = (const float*)d_in[2];  // (512,384)
  const float* w_hh   = (const float*)d_in[3];  // (512,128)
  const float* b_ih   = (const float*)d_in[4];  // (512)
  const float* b_hh   = (const float*)d_in[5];  // (512)
  const float* w_proj = (const float*)d_in[6];  // (384,128)
  const float* b_proj = (const float*)d_in[7];  // (384)
  float* out = (float*)d_out;                   // (1024,384,1,1) fp32

  float* seq = (float*)d_ws;                                   // 5120*384 f32
  float* G   = seq + (size_t)N_SAMP * NHIST * C_TRUNK;         // 5120*512 f32

  prep_kernel<<<N_SAMP, 256, 0, stream>>>(inp, trunk, seq);
  gates_kernel<<<dim3(NGATE / BN, (N_SAMP * NHIST) / BM), 256, 0, stream>>>(
      seq, w_ih, b_ih, b_hh, G);
  lstm_kernel<<<N_SAMP / 4, 128, 0, stream>>>(G, w_hh, w_proj, b_proj, out);
}

// Round 2
// 153.066 us; speedup vs baseline: 1.1801x; 1.1801x over previous
//
#include <hip/hip_runtime.h>
#include <hip/hip_bf16.h>
#include <float.h>

#define N_SAMP   1024
#define C_IN     22
#define HW       361
#define C_TRUNK  384
#define HID      128
#define NHIST    5
#define HIST_START 9
#define NGATE    512   // 4*HID

// ---------------- Kernel 0: aux — bias sum + w_proj transpose ----------------
__global__ __launch_bounds__(256) void aux_kernel(
    const float* __restrict__ w_proj,  // (384,128)
    const float* __restrict__ b_ih,    // (512)
    const float* __restrict__ b_hh,    // (512)
    float* __restrict__ wpT,           // (128,384)
    float* __restrict__ bias)          // (512)
{
  int i = blockIdx.x * 256 + threadIdx.x;
  if (i < NGATE) bias[i] = b_ih[i] + b_hh[i];
  if (i < C_TRUNK * HID) {
    int cc = i >> 7;          // 0..383
    int k  = i & 127;         // 0..127
    wpT[k * C_TRUNK + cc] = w_proj[i];
  }
}

// ---------------- Kernel 1: argmax + sum + gather (with reversal/masking) ----
__global__ __launch_bounds__(256) void prep_kernel(
    const float* __restrict__ inp,      // (N, 22, 361)
    const float* __restrict__ trunk,    // (N, 384, 361)
    float* __restrict__ seq)            // (N, 5, 384)  already reversed+masked
{
  const int n   = blockIdx.x;
  const int tid = threadIdx.x;
  __shared__ float sv[256];
  __shared__ int   si[256];
  __shared__ float ss[256];
  __shared__ int   plane_idx[NHIST];
  __shared__ float plane_move[NHIST];

  for (int t = 0; t < NHIST; ++t) {
    const float* base = inp + ((size_t)n * C_IN + HIST_START + t) * HW;
    float v = -FLT_MAX; int vi = 0x7fffffff; float sum = 0.f;
    for (int i = tid; i < HW; i += 256) {
      float x = base[i];
      sum += x;
      if (x > v) { v = x; vi = i; }
    }
    sv[tid] = v; si[tid] = vi; ss[tid] = sum;
    __syncthreads();
    for (int off = 128; off > 0; off >>= 1) {
      if (tid < off) {
        float v2 = sv[tid + off]; int i2 = si[tid + off];
        if (v2 > sv[tid] || (v2 == sv[tid] && i2 < si[tid])) { sv[tid] = v2; si[tid] = i2; }
        ss[tid] += ss[tid + off];
      }
      __syncthreads();
    }
    if (tid == 0) {
      plane_idx[t]  = si[0];
      plane_move[t] = (ss[0] > 0.5f) ? 1.f : 0.f;
    }
    __syncthreads();
  }

  for (int e = tid; e < NHIST * C_TRUNK; e += 256) {
    int t = e / C_TRUNK;
    int c = e - t * C_TRUNK;
    int rawt = NHIST - 1 - t;
    int p    = plane_idx[rawt];
    float m  = plane_move[rawt];
    seq[((size_t)n * NHIST + t) * C_TRUNK + c] =
        m * trunk[((size_t)n * C_TRUNK + c) * HW + p];
  }
}

// ---------------- Kernel 2: G = seq @ w_ih^T + bias --------------------------
// M=5120, N=512, K=384. BM=64, BN=128, BK=32, 256 threads, 8x4 microtile.
#define GBM 64
#define GBN 128
#define GBK 32

__global__ __launch_bounds__(256) void gates_kernel(
    const float* __restrict__ seq,   // (5120, 384)
    const float* __restrict__ w_ih,  // (512, 384)
    const float* __restrict__ bias,  // (512) = b_ih + b_hh
    float* __restrict__ G)           // (5120, 512)
{
  __shared__ float As[GBK][68];    // [k][m-row], pad 68 keeps 16B align + spreads banks
  __shared__ float Bs[GBK][132];   // [k][n-row]
  const int tid = threadIdx.x;
  const int m0 = blockIdx.y * GBM;
  const int j0 = blockIdx.x * GBN;
  const int tx = tid & 31;         // 0..31 -> 4 output cols
  const int ty = tid >> 5;         // 0..7  -> 8 output rows

  float acc[8][4];
  #pragma unroll
  for (int i = 0; i < 8; ++i)
    #pragma unroll
    for (int j = 0; j < 4; ++j) acc[i][j] = 0.f;

  for (int k0 = 0; k0 < C_TRUNK; k0 += GBK) {
    // A tile: 64 rows x 32 k = 512 float4
    #pragma unroll
    for (int l = 0; l < 2; ++l) {
      int id  = tid + l * 256;
      int row = id >> 3, kq = id & 7;
      float4 a = *(const float4*)(seq + (size_t)(m0 + row) * C_TRUNK + k0 + kq * 4);
      As[kq*4+0][row] = a.x; As[kq*4+1][row] = a.y;
      As[kq*4+2][row] = a.z; As[kq*4+3][row] = a.w;
    }
    // B tile: 128 rows x 32 k = 1024 float4
    #pragma unroll
    for (int l = 0; l < 4; ++l) {
      int id  = tid + l * 256;
      int row = id >> 3, kq = id & 7;
      float4 b = *(const float4*)(w_ih + (size_t)(j0 + row) * C_TRUNK + k0 + kq * 4);
      Bs[kq*4+0][row] = b.x; Bs[kq*4+1][row] = b.y;
      Bs[kq*4+2][row] = b.z; Bs[kq*4+3][row] = b.w;
    }
    __syncthreads();
    #pragma unroll 8
    for (int k = 0; k < GBK; ++k) {
      float4 a0 = *(const float4*)&As[k][ty * 8];
      float4 a1 = *(const float4*)&As[k][ty * 8 + 4];
      float4 b0 = *(const float4*)&Bs[k][tx * 4];
      float av[8] = {a0.x, a0.y, a0.z, a0.w, a1.x, a1.y, a1.z, a1.w};
      float bv[4] = {b0.x, b0.y, b0.z, b0.w};
      #pragma unroll
      for (int i = 0; i < 8; ++i)
        #pragma unroll
        for (int j = 0; j < 4; ++j) acc[i][j] += av[i] * bv[j];
    }
    __syncthreads();
  }

  float4 bz = *(const float4*)(bias + j0 + tx * 4);
  #pragma unroll
  for (int i = 0; i < 8; ++i) {
    float4 o;
    o.x = acc[i][0] + bz.x; o.y = acc[i][1] + bz.y;
    o.z = acc[i][2] + bz.z; o.w = acc[i][3] + bz.w;
    *(float4*)(G + (size_t)(m0 + ty * 8 + i) * NGATE + j0 + tx * 4) = o;
  }
}

// ---------------- Kernel 3: recurrence + projection ---------------------------
// 4 samples/block, 512 threads (8 waves). Thread (g=tid>>7, j=tid&127) holds
// w_hh row g*128+j in 128 VGPRs (loaded once, fully unrolled -> stays in regs).
__global__ __launch_bounds__(512, 2) void lstm_kernel(
    const float* __restrict__ G,       // (1024, 5, 512)
    const float* __restrict__ w_hh,    // (512, 128)
    const float* __restrict__ wpT,     // (128, 384)  transposed w_proj
    const float* __restrict__ b_proj,  // (384)
    float* __restrict__ out)           // (1024, 384)
{
  const int n0  = blockIdx.x * 4;
  const int tid = threadIdx.x;
  const int g   = tid >> 7;     // gate 0..3
  const int j   = tid & 127;    // hidden unit

  __shared__ float hs[4][HID];            // [sample][unit]
  __shared__ float glds[4][4][HID];       // [gate][sample][unit]

  float4 wreg[32];
  #pragma unroll
  for (int k4 = 0; k4 < 32; ++k4)
    wreg[k4] = *(const float4*)(w_hh + (size_t)(g * HID + j) * HID + k4 * 4);

  hs[g][j] = 0.f;              // 4x128 covered exactly by 512 threads
  float c = 0.f;               // thread (g,j) owns cell state of sample s=g, unit j
  __syncthreads();

  for (int t = 0; t < NHIST; ++t) {
    float a[4];
    #pragma unroll
    for (int s = 0; s < 4; ++s)
      a[s] = G[((size_t)(n0 + s) * NHIST + t) * NGATE + tid];  // tid == g*128+j

    #pragma unroll
    for (int k4 = 0; k4 < 32; ++k4) {
      float4 w = wreg[k4];
      #pragma unroll
      for (int s = 0; s < 4; ++s) {
        float4 h = *(const float4*)&hs[s][k4 * 4];   // broadcast read
        a[s] += w.x * h.x + w.y * h.y + w.z * h.z + w.w * h.w;
      }
    }
    #pragma unroll
    for (int s = 0; s < 4; ++s) glds[g][s][j] = a[s];
    __syncthreads();
    {
      float ig = glds[0][g][j];
      float fg = glds[1][g][j];
      float gg = glds[2][g][j];
      float og = glds[3][g][j];
      ig = 1.f / (1.f + __expf(-ig));
      fg = 1.f / (1.f + __expf(-fg));
      og = 1.f / (1.f + __expf(-og));
      c  = fg * c + ig * tanhf(gg);
      hs[g][j] = og * tanhf(c);
    }
    __syncthreads();
  }

  // projection: thread cc<384 accumulates 4 samples, wpT read coalesced once
  if (tid < C_TRUNK) {
    const int cc = tid;
    float b = b_proj[cc];
    float po[4] = {b, b, b, b};
    for (int k = 0; k < HID; ++k) {
      float w = wpT[(size_t)k * C_TRUNK + cc];
      #pragma unroll
      for (int s = 0; s < 4; ++s) po[s] += hs[s][k] * w;
    }
    #pragma unroll
    for (int s = 0; s < 4; ++s)
      out[(size_t)(n0 + s) * C_TRUNK + cc] = po[s];
  }
}

extern "C" void kernel_launch(void* const* d_in, const int* in_sizes, int n_in,
                              void* d_out, int out_size, void* d_ws, size_t ws_size,
                              hipStream_t stream) {
  const float* inp    = (const float*)d_in[0];
  const float* trunk  = (const float*)d_in[1];
  const float* w_ih   = (const float*)d_in[2];
  const float* w_hh   = (const float*)d_in[3];
  const float* b_ih   = (const float*)d_in[4];
  const float* b_hh   = (const float*)d_in[5];
  const float* w_proj = (const float*)d_in[6];
  const float* b_proj = (const float*)d_in[7];
  float* out = (float*)d_out;

  float* seq  = (float*)d_ws;                                   // 5120*384
  float* G    = seq  + (size_t)N_SAMP * NHIST * C_TRUNK;        // 5120*512
  float* wpT  = G    + (size_t)N_SAMP * NHIST * NGATE;          // 128*384
  float* bias = wpT  + (size_t)HID * C_TRUNK;                   // 512

  aux_kernel<<<192, 256, 0, stream>>>(w_proj, b_ih, b_hh, wpT, bias);
  prep_kernel<<<N_SAMP, 256, 0, stream>>>(inp, trunk, seq);
  gates_kernel<<<dim3(NGATE / GBN, (N_SAMP * NHIST) / GBM), 256, 0, stream>>>(
      seq, w_ih, bias, G);
  lstm_kernel<<<N_SAMP / 4, 512, 0, stream>>>(G, w_hh, wpT, b_proj, out);
}

// Round 3
// 132.397 us; speedup vs baseline: 1.3643x; 1.1561x over previous
//
#include <hip/hip_runtime.h>
#include <hip/hip_bf16.h>
#include <float.h>

#define N_SAMP   1024
#define C_IN     22
#define HW       361
#define C_TRUNK  384
#define HID      128
#define NHIST    5
#define HIST_START 9
#define NGATE    512   // 4*HID

// ---------------- Kernel 1: argmax + sum + gather (reversal + masking) -------
// 384 threads = 6 waves. Waves 0..4 each reduce one history plane with a
// shuffle butterfly (no LDS reduction, 1 syncthreads total). Gather is
// c-major: thread c issues all 5 t-loads of its trunk row back-to-back
// (same 1444B row -> same DRAM page, 5-deep MLP, L1 line reuse).
__global__ __launch_bounds__(384) void prep_kernel(
    const float* __restrict__ inp,      // (N, 22, 361)
    const float* __restrict__ trunk,    // (N, 384, 361)
    float* __restrict__ seq)            // (N, 5, 384) reversed + masked
{
  const int n    = blockIdx.x;
  const int tid  = threadIdx.x;
  const int wave = tid >> 6;
  const int lane = tid & 63;
  __shared__ int   s_idx[NHIST];
  __shared__ float s_mov[NHIST];

  if (wave < NHIST) {
    const float* base = inp + ((size_t)n * C_IN + HIST_START + wave) * HW;
    float v = -FLT_MAX; int vi = 0; float sum = 0.f;
    #pragma unroll
    for (int r = 0; r < 6; ++r) {
      int i = lane + r * 64;
      if (i < HW) {
        float x = base[i];
        sum += x;
        if (x > v) { v = x; vi = i; }   // strict > keeps first occurrence
      }
    }
    #pragma unroll
    for (int m = 1; m < 64; m <<= 1) {
      float v2 = __shfl_xor(v, m);
      int   i2 = __shfl_xor(vi, m);
      float s2 = __shfl_xor(sum, m);
      if (v2 > v || (v2 == v && i2 < vi)) { v = v2; vi = i2; }  // min idx on tie
      sum += s2;
    }
    if (lane == 0) { s_idx[wave] = vi; s_mov[wave] = (sum > 0.5f) ? 1.f : 0.f; }
  }
  __syncthreads();

  if (tid < C_TRUNK) {
    const float* tb = trunk + ((size_t)n * C_TRUNK + tid) * HW;
    int   i0 = s_idx[4], i1 = s_idx[3], i2 = s_idx[2], i3 = s_idx[1], i4 = s_idx[0];
    float m0 = s_mov[4], m1 = s_mov[3], m2 = s_mov[2], m3 = s_mov[1], m4 = s_mov[0];
    float x0 = tb[i0], x1 = tb[i1], x2 = tb[i2], x3 = tb[i3], x4 = tb[i4];
    float* so = seq + (size_t)n * NHIST * C_TRUNK + tid;
    so[0 * C_TRUNK] = x0 * m0;   // seq[t] = feats[4-t]
    so[1 * C_TRUNK] = x1 * m1;
    so[2 * C_TRUNK] = x2 * m2;
    so[3 * C_TRUNK] = x3 * m3;
    so[4 * C_TRUNK] = x4 * m4;
  }
}

// ---------------- Kernel 2: G = seq @ w_ih^T + b_ih + b_hh -------------------
// M=5120, N=512, K=384. BM=64, BN=128, BK=32, 256 threads, 8x4 microtile.
#define GBM 64
#define GBN 128
#define GBK 32

__global__ __launch_bounds__(256) void gates_kernel(
    const float* __restrict__ seq,   // (5120, 384)
    const float* __restrict__ w_ih,  // (512, 384)
    const float* __restrict__ b_ih,  // (512)
    const float* __restrict__ b_hh,  // (512)
    float* __restrict__ G)           // (5120, 512)
{
  __shared__ float As[GBK][68];
  __shared__ float Bs[GBK][132];
  const int tid = threadIdx.x;
  const int m0 = blockIdx.y * GBM;
  const int j0 = blockIdx.x * GBN;
  const int tx = tid & 31;
  const int ty = tid >> 5;

  float acc[8][4];
  #pragma unroll
  for (int i = 0; i < 8; ++i)
    #pragma unroll
    for (int j = 0; j < 4; ++j) acc[i][j] = 0.f;

  for (int k0 = 0; k0 < C_TRUNK; k0 += GBK) {
    #pragma unroll
    for (int l = 0; l < 2; ++l) {
      int id  = tid + l * 256;
      int row = id >> 3, kq = id & 7;
      float4 a = *(const float4*)(seq + (size_t)(m0 + row) * C_TRUNK + k0 + kq * 4);
      As[kq*4+0][row] = a.x; As[kq*4+1][row] = a.y;
      As[kq*4+2][row] = a.z; As[kq*4+3][row] = a.w;
    }
    #pragma unroll
    for (int l = 0; l < 4; ++l) {
      int id  = tid + l * 256;
      int row = id >> 3, kq = id & 7;
      float4 b = *(const float4*)(w_ih + (size_t)(j0 + row) * C_TRUNK + k0 + kq * 4);
      Bs[kq*4+0][row] = b.x; Bs[kq*4+1][row] = b.y;
      Bs[kq*4+2][row] = b.z; Bs[kq*4+3][row] = b.w;
    }
    __syncthreads();
    #pragma unroll 8
    for (int k = 0; k < GBK; ++k) {
      float4 a0 = *(const float4*)&As[k][ty * 8];
      float4 a1 = *(const float4*)&As[k][ty * 8 + 4];
      float4 b0 = *(const float4*)&Bs[k][tx * 4];
      float av[8] = {a0.x, a0.y, a0.z, a0.w, a1.x, a1.y, a1.z, a1.w};
      float bv[4] = {b0.x, b0.y, b0.z, b0.w};
      #pragma unroll
      for (int i = 0; i < 8; ++i)
        #pragma unroll
        for (int j = 0; j < 4; ++j) acc[i][j] += av[i] * bv[j];
    }
    __syncthreads();
  }

  float4 b1 = *(const float4*)(b_ih + j0 + tx * 4);
  float4 b2 = *(const float4*)(b_hh + j0 + tx * 4);
  #pragma unroll
  for (int i = 0; i < 8; ++i) {
    float4 o;
    o.x = acc[i][0] + b1.x + b2.x; o.y = acc[i][1] + b1.y + b2.y;
    o.z = acc[i][2] + b1.z + b2.z; o.w = acc[i][3] + b1.w + b2.w;
    *(float4*)(G + (size_t)(m0 + ty * 8 + i) * NGATE + j0 + tx * 4) = o;
  }
}

// ---------------- Kernel 3: recurrence + projection ---------------------------
// 4 samples/block, 512 threads. Thread (g=tid>>7, j=tid&127) holds w_hh row
// g*128+j in 128 VGPRs (fully unrolled static indexing -> stays in registers).
__global__ __launch_bounds__(512, 2) void lstm_kernel(
    const float* __restrict__ G,       // (1024, 5, 512)
    const float* __restrict__ w_hh,    // (512, 128)
    const float* __restrict__ w_proj,  // (384, 128)
    const float* __restrict__ b_proj,  // (384)
    float* __restrict__ out)           // (1024, 384)
{
  const int n0  = blockIdx.x * 4;
  const int tid = threadIdx.x;
  const int g   = tid >> 7;
  const int j   = tid & 127;

  __shared__ float hs[4][HID];
  __shared__ float glds[4][4][HID];

  float4 wreg[32];
  #pragma unroll
  for (int k4 = 0; k4 < 32; ++k4)
    wreg[k4] = *(const float4*)(w_hh + (size_t)(g * HID + j) * HID + k4 * 4);

  hs[g][j] = 0.f;
  float c = 0.f;
  __syncthreads();

  for (int t = 0; t < NHIST; ++t) {
    float a[4];
    #pragma unroll
    for (int s = 0; s < 4; ++s)
      a[s] = G[((size_t)(n0 + s) * NHIST + t) * NGATE + tid];

    #pragma unroll
    for (int k4 = 0; k4 < 32; ++k4) {
      float4 w = wreg[k4];
      #pragma unroll
      for (int s = 0; s < 4; ++s) {
        float4 h = *(const float4*)&hs[s][k4 * 4];
        a[s] += w.x * h.x + w.y * h.y + w.z * h.z + w.w * h.w;
      }
    }
    #pragma unroll
    for (int s = 0; s < 4; ++s) glds[g][s][j] = a[s];
    __syncthreads();
    {
      float ig = glds[0][g][j];
      float fg = glds[1][g][j];
      float gg = glds[2][g][j];
      float og = glds[3][g][j];
      ig = 1.f / (1.f + __expf(-ig));
      fg = 1.f / (1.f + __expf(-fg));
      og = 1.f / (1.f + __expf(-og));
      c  = fg * c + ig * tanhf(gg);
      hs[g][j] = og * tanhf(c);
    }
    __syncthreads();
  }

  // projection: thread cc accumulates 4 samples; w_proj row is 512B contiguous
  // per thread (float4 x32) -> L1 line reuse across the 4 steps per line.
  if (tid < C_TRUNK) {
    const int cc = tid;
    const float4* wp = (const float4*)(w_proj + (size_t)cc * HID);
    float b = b_proj[cc];
    float po[4] = {b, b, b, b};
    #pragma unroll 8
    for (int k4 = 0; k4 < 32; ++k4) {
      float4 w  = wp[k4];
      float4 h0 = *(const float4*)&hs[0][k4 * 4];
      float4 h1 = *(const float4*)&hs[1][k4 * 4];
      float4 h2 = *(const float4*)&hs[2][k4 * 4];
      float4 h3 = *(const float4*)&hs[3][k4 * 4];
      po[0] += w.x*h0.x + w.y*h0.y + w.z*h0.z + w.w*h0.w;
      po[1] += w.x*h1.x + w.y*h1.y + w.z*h1.z + w.w*h1.w;
      po[2] += w.x*h2.x + w.y*h2.y + w.z*h2.z + w.w*h2.w;
      po[3] += w.x*h3.x + w.y*h3.y + w.z*h3.z + w.w*h3.w;
    }
    #pragma unroll
    for (int s = 0; s < 4; ++s)
      out[(size_t)(n0 + s) * C_TRUNK + cc] = po[s];
  }
}

extern "C" void kernel_launch(void* const* d_in, const int* in_sizes, int n_in,
                              void* d_out, int out_size, void* d_ws, size_t ws_size,
                              hipStream_t stream) {
  const float* inp    = (const float*)d_in[0];
  const float* trunk  = (const float*)d_in[1];
  const float* w_ih   = (const float*)d_in[2];
  const float* w_hh   = (const float*)d_in[3];
  const float* b_ih   = (const float*)d_in[4];
  const float* b_hh   = (const float*)d_in[5];
  const float* w_proj = (const float*)d_in[6];
  const float* b_proj = (const float*)d_in[7];
  float* out = (float*)d_out;

  float* seq = (float*)d_ws;                                   // 5120*384 f32
  float* G   = seq + (size_t)N_SAMP * NHIST * C_TRUNK;         // 5120*512 f32

  prep_kernel<<<N_SAMP, 384, 0, stream>>>(inp, trunk, seq);
  gates_kernel<<<dim3(NGATE / GBN, (N_SAMP * NHIST) / GBM), 256, 0, stream>>>(
      seq, w_ih, b_ih, b_hh, G);
  lstm_kernel<<<N_SAMP / 4, 512, 0, stream>>>(G, w_hh, w_proj, b_proj, out);
}

// Round 4
// 94.744 us; speedup vs baseline: 1.9066x; 1.3974x over previous
//
#include <hip/hip_runtime.h>
#include <hip/hip_bf16.h>
#include <float.h>

#define N_SAMP   1024
#define C_IN     22
#define HW       361
#define C_TRUNK  384
#define HID      128
#define NHIST    5
#define HIST_START 9
#define NGATE    512   // 4*HID

typedef __attribute__((ext_vector_type(8))) short short8v;
typedef __attribute__((ext_vector_type(4))) float float4v;

static __device__ __forceinline__ ushort f2bf(float x) {
  // RNE fp32 -> bf16 (finite inputs)
  unsigned int b = __float_as_uint(x);
  b += 0x7fffu + ((b >> 16) & 1u);
  return (ushort)(b >> 16);
}

// ---------------- Kernel 1: argmax + sum + gather (reversal + masking) -------
// 384 threads = 6 waves. Waves 0..4 reduce one plane each (shuffle butterfly).
// Gather is c-major: thread c issues all 5 t-loads of its trunk row
// back-to-back. seq is written as bf16 (feeds the MFMA gates GEMM).
__global__ __launch_bounds__(384) void prep_kernel(
    const float* __restrict__ inp,      // (N, 22, 361)
    const float* __restrict__ trunk,    // (N, 384, 361)
    ushort* __restrict__ seq)           // (N, 5, 384) bf16, reversed + masked
{
  const int n    = blockIdx.x;
  const int tid  = threadIdx.x;
  const int wave = tid >> 6;
  const int lane = tid & 63;
  __shared__ int   s_idx[NHIST];
  __shared__ float s_mov[NHIST];

  if (wave < NHIST) {
    const float* base = inp + ((size_t)n * C_IN + HIST_START + wave) * HW;
    float v = -FLT_MAX; int vi = 0; float sum = 0.f;
    #pragma unroll
    for (int r = 0; r < 6; ++r) {
      int i = lane + r * 64;
      if (i < HW) {
        float x = base[i];
        sum += x;
        if (x > v) { v = x; vi = i; }   // strict > keeps first occurrence
      }
    }
    #pragma unroll
    for (int m = 1; m < 64; m <<= 1) {
      float v2 = __shfl_xor(v, m);
      int   i2 = __shfl_xor(vi, m);
      float s2 = __shfl_xor(sum, m);
      if (v2 > v || (v2 == v && i2 < vi)) { v = v2; vi = i2; }  // min idx on tie
      sum += s2;
    }
    if (lane == 0) { s_idx[wave] = vi; s_mov[wave] = (sum > 0.5f) ? 1.f : 0.f; }
  }
  __syncthreads();

  if (tid < C_TRUNK) {
    const float* tb = trunk + ((size_t)n * C_TRUNK + tid) * HW;
    int   i0 = s_idx[4], i1 = s_idx[3], i2 = s_idx[2], i3 = s_idx[1], i4 = s_idx[0];
    float m0 = s_mov[4], m1 = s_mov[3], m2 = s_mov[2], m3 = s_mov[1], m4 = s_mov[0];
    float x0 = tb[i0], x1 = tb[i1], x2 = tb[i2], x3 = tb[i3], x4 = tb[i4];
    ushort* so = seq + (size_t)n * NHIST * C_TRUNK + tid;
    so[0 * C_TRUNK] = f2bf(x0 * m0);   // seq[t] = feats[4-t]
    so[1 * C_TRUNK] = f2bf(x1 * m1);
    so[2 * C_TRUNK] = f2bf(x2 * m2);
    so[3 * C_TRUNK] = f2bf(x3 * m3);
    so[4 * C_TRUNK] = f2bf(x4 * m4);
  }
}

// ---------------- Kernel 2: G = seq @ w_ih^T + b_ih + b_hh  (bf16 MFMA) ------
// M=5120, N=512, K=384. BM=BN=64, BK=32, 256 threads = 4 waves.
// Wave w computes rows w*16..w*16+15 x all 64 cols (4 col-frags of 16).
// mfma_f32_16x16x32_bf16: A row=lane%16, k=(lane/16)*8+j; C/D col=lane&15,
// row=(lane>>4)*4+reg (m89-verified).
__global__ __launch_bounds__(256) void gates_kernel(
    const ushort* __restrict__ seq,  // (5120, 384) bf16
    const float* __restrict__ w_ih,  // (512, 384) fp32
    const float* __restrict__ b_ih,  // (512)
    const float* __restrict__ b_hh,  // (512)
    float* __restrict__ G)           // (5120, 512) fp32
{
  __shared__ ushort As[64][40];   // 64 rows x 32 k (+8 pad: 80B row stride)
  __shared__ ushort Bs[64][40];   // 64 cols x 32 k
  const int tid  = threadIdx.x;
  const int wv   = tid >> 6;
  const int lane = tid & 63;
  const int m0 = blockIdx.y * 64;
  const int j0 = blockIdx.x * 64;
  const int row_l = tid >> 2;          // 0..63 staging row
  const int koff  = (tid & 3) * 8;     // bf16-k offset {0,8,16,24}

  float4v acc0 = {0.f,0.f,0.f,0.f};
  float4v acc1 = {0.f,0.f,0.f,0.f};
  float4v acc2 = {0.f,0.f,0.f,0.f};
  float4v acc3 = {0.f,0.f,0.f,0.f};

  const int fr = lane & 15;        // frag row/col
  const int fk = (lane >> 4) * 8;  // frag k base

  for (int k0 = 0; k0 < C_TRUNK; k0 += 32) {
    // A tile: already bf16, 16B per thread
    *(short8v*)&As[row_l][koff] =
        *(const short8v*)(seq + (size_t)(m0 + row_l) * C_TRUNK + k0 + koff);
    // B tile: 8 fp32 -> 8 bf16 per thread
    const float* wp = w_ih + (size_t)(j0 + row_l) * C_TRUNK + k0 + koff;
    float4 w0 = *(const float4*)wp;
    float4 w1 = *(const float4*)(wp + 4);
    short8v bvec;
    bvec[0] = (short)f2bf(w0.x); bvec[1] = (short)f2bf(w0.y);
    bvec[2] = (short)f2bf(w0.z); bvec[3] = (short)f2bf(w0.w);
    bvec[4] = (short)f2bf(w1.x); bvec[5] = (short)f2bf(w1.y);
    bvec[6] = (short)f2bf(w1.z); bvec[7] = (short)f2bf(w1.w);
    *(short8v*)&Bs[row_l][koff] = bvec;
    __syncthreads();

    short8v af = *(const short8v*)&As[wv * 16 + fr][fk];
    short8v bf0 = *(const short8v*)&Bs[ 0 + fr][fk];
    short8v bf1 = *(const short8v*)&Bs[16 + fr][fk];
    short8v bf2 = *(const short8v*)&Bs[32 + fr][fk];
    short8v bf3 = *(const short8v*)&Bs[48 + fr][fk];
    acc0 = __builtin_amdgcn_mfma_f32_16x16x32_bf16(af, bf0, acc0, 0, 0, 0);
    acc1 = __builtin_amdgcn_mfma_f32_16x16x32_bf16(af, bf1, acc1, 0, 0, 0);
    acc2 = __builtin_amdgcn_mfma_f32_16x16x32_bf16(af, bf2, acc2, 0, 0, 0);
    acc3 = __builtin_amdgcn_mfma_f32_16x16x32_bf16(af, bf3, acc3, 0, 0, 0);
    __syncthreads();
  }

  // epilogue: D col = lane&15, row = (lane>>4)*4 + reg
  const int rbase = m0 + wv * 16 + (lane >> 4) * 4;
  #pragma unroll
  for (int j = 0; j < 4; ++j) {
    const float4v a = (j == 0) ? acc0 : (j == 1) ? acc1 : (j == 2) ? acc2 : acc3;
    const int cj = j0 + j * 16 + fr;
    const float bsum = b_ih[cj] + b_hh[cj];
    #pragma unroll
    for (int r = 0; r < 4; ++r)
      G[(size_t)(rbase + r) * NGATE + cj] = a[r] + bsum;
  }
}

// ---------------- Kernel 3: recurrence + projection (fp32, unchanged) --------
__global__ __launch_bounds__(512, 2) void lstm_kernel(
    const float* __restrict__ G,       // (1024, 5, 512)
    const float* __restrict__ w_hh,    // (512, 128)
    const float* __restrict__ w_proj,  // (384, 128)
    const float* __restrict__ b_proj,  // (384)
    float* __restrict__ out)           // (1024, 384)
{
  const int n0  = blockIdx.x * 4;
  const int tid = threadIdx.x;
  const int g   = tid >> 7;
  const int j   = tid & 127;

  __shared__ float hs[4][HID];
  __shared__ float glds[4][4][HID];

  float4 wreg[32];
  #pragma unroll
  for (int k4 = 0; k4 < 32; ++k4)
    wreg[k4] = *(const float4*)(w_hh + (size_t)(g * HID + j) * HID + k4 * 4);

  hs[g][j] = 0.f;
  float c = 0.f;
  __syncthreads();

  for (int t = 0; t < NHIST; ++t) {
    float a[4];
    #pragma unroll
    for (int s = 0; s < 4; ++s)
      a[s] = G[((size_t)(n0 + s) * NHIST + t) * NGATE + tid];

    #pragma unroll
    for (int k4 = 0; k4 < 32; ++k4) {
      float4 w = wreg[k4];
      #pragma unroll
      for (int s = 0; s < 4; ++s) {
        float4 h = *(const float4*)&hs[s][k4 * 4];
        a[s] += w.x * h.x + w.y * h.y + w.z * h.z + w.w * h.w;
      }
    }
    #pragma unroll
    for (int s = 0; s < 4; ++s) glds[g][s][j] = a[s];
    __syncthreads();
    {
      float ig = glds[0][g][j];
      float fg = glds[1][g][j];
      float gg = glds[2][g][j];
      float og = glds[3][g][j];
      ig = 1.f / (1.f + __expf(-ig));
      fg = 1.f / (1.f + __expf(-fg));
      og = 1.f / (1.f + __expf(-og));
      c  = fg * c + ig * tanhf(gg);
      hs[g][j] = og * tanhf(c);
    }
    __syncthreads();
  }

  if (tid < C_TRUNK) {
    const int cc = tid;
    const float4* wp = (const float4*)(w_proj + (size_t)cc * HID);
    float b = b_proj[cc];
    float po[4] = {b, b, b, b};
    #pragma unroll 8
    for (int k4 = 0; k4 < 32; ++k4) {
      float4 w  = wp[k4];
      float4 h0 = *(const float4*)&hs[0][k4 * 4];
      float4 h1 = *(const float4*)&hs[1][k4 * 4];
      float4 h2 = *(const float4*)&hs[2][k4 * 4];
      float4 h3 = *(const float4*)&hs[3][k4 * 4];
      po[0] += w.x*h0.x + w.y*h0.y + w.z*h0.z + w.w*h0.w;
      po[1] += w.x*h1.x + w.y*h1.y + w.z*h1.z + w.w*h1.w;
      po[2] += w.x*h2.x + w.y*h2.y + w.z*h2.z + w.w*h2.w;
      po[3] += w.x*h3.x + w.y*h3.y + w.z*h3.z + w.w*h3.w;
    }
    #pragma unroll
    for (int s = 0; s < 4; ++s)
      out[(size_t)(n0 + s) * C_TRUNK + cc] = po[s];
  }
}

extern "C" void kernel_launch(void* const* d_in, const int* in_sizes, int n_in,
                              void* d_out, int out_size, void* d_ws, size_t ws_size,
                              hipStream_t stream) {
  const float* inp    = (const float*)d_in[0];
  const float* trunk  = (const float*)d_in[1];
  const float* w_ih   = (const float*)d_in[2];
  const float* w_hh   = (const float*)d_in[3];
  const float* b_ih   = (const float*)d_in[4];
  const float* b_hh   = (const float*)d_in[5];
  const float* w_proj = (const float*)d_in[6];
  const float* b_proj = (const float*)d_in[7];
  float* out = (float*)d_out;

  ushort* seq = (ushort*)d_ws;                                  // 5120*384 bf16
  float*  G   = (float*)((char*)d_ws +
                 (size_t)N_SAMP * NHIST * C_TRUNK * sizeof(ushort)); // 5120*512 f32

  prep_kernel<<<N_SAMP, 384, 0, stream>>>(inp, trunk, seq);
  gates_kernel<<<dim3(NGATE / 64, (N_SAMP * NHIST) / 64), 256, 0, stream>>>(
      seq, w_ih, b_ih, b_hh, G);
  lstm_kernel<<<N_SAMP / 4, 512, 0, stream>>>(G, w_hh, w_proj, b_proj, out);
}

// Round 5
// 86.332 us; speedup vs baseline: 2.0923x; 1.0974x over previous
//
#include <hip/hip_runtime.h>
#include <hip/hip_bf16.h>
#include <float.h>

#define N_SAMP   1024
#define C_IN     22
#define HW       361
#define C_TRUNK  384
#define HID      128
#define NHIST    5
#define HIST_START 9
#define NGATE    512   // 4*HID

typedef __attribute__((ext_vector_type(8))) short short8v;
typedef __attribute__((ext_vector_type(4))) float float4v;

static __device__ __forceinline__ ushort f2bf(float x) {
  unsigned int b = __float_as_uint(x);
  b += 0x7fffu + ((b >> 16) & 1u);
  return (ushort)(b >> 16);
}

// ---------------- Kernel A: per-(sample,plane) argmax + movement flag --------
// 1024 blocks x 320 threads (5 waves). Wave t reduces history plane t with a
// shuffle butterfly; writes idx and move flag to workspace.
__global__ __launch_bounds__(320) void argmax_kernel(
    const float* __restrict__ inp,   // (N, 22, 361)
    int*   __restrict__ idxb,        // (N, 5)
    float* __restrict__ movb)        // (N, 5)
{
  const int n    = blockIdx.x;
  const int wave = threadIdx.x >> 6;   // 0..4
  const int lane = threadIdx.x & 63;

  const float* base = inp + ((size_t)n * C_IN + HIST_START + wave) * HW;
  float v = -FLT_MAX; int vi = 0; float sum = 0.f;
  #pragma unroll
  for (int r = 0; r < 6; ++r) {
    int i = lane + r * 64;
    if (i < HW) {
      float x = base[i];
      sum += x;
      if (x > v) { v = x; vi = i; }   // strict > keeps first occurrence
    }
  }
  #pragma unroll
  for (int m = 1; m < 64; m <<= 1) {
    float v2 = __shfl_xor(v, m);
    int   i2 = __shfl_xor(vi, m);
    float s2 = __shfl_xor(sum, m);
    if (v2 > v || (v2 == v && i2 < vi)) { v = v2; vi = i2; }  // min idx on tie
    sum += s2;
  }
  if (lane == 0) {
    idxb[n * NHIST + wave] = vi;
    movb[n * NHIST + wave] = (sum > 0.5f) ? 1.f : 0.f;
  }
}

// ---------------- Kernel B: gather (reversal + masking), pure scatter --------
// 1024 blocks x 384 threads. Thread c issues its 5 row-local loads
// back-to-back (same 1444B trunk row -> same DRAM page, 5-deep MLP).
// idx/move loads are wave-uniform -> s_load broadcast.
__global__ __launch_bounds__(384) void gather_kernel(
    const float* __restrict__ trunk,  // (N, 384, 361)
    const int*   __restrict__ idxb,   // (N, 5)
    const float* __restrict__ movb,   // (N, 5)
    ushort* __restrict__ seq)         // (N, 5, 384) bf16, reversed + masked
{
  const int n = blockIdx.x;
  const int c = threadIdx.x;           // 0..383

  const int   i0 = idxb[n * NHIST + 4], i1 = idxb[n * NHIST + 3],
              i2 = idxb[n * NHIST + 2], i3 = idxb[n * NHIST + 1],
              i4 = idxb[n * NHIST + 0];
  const float m0 = movb[n * NHIST + 4], m1 = movb[n * NHIST + 3],
              m2 = movb[n * NHIST + 2], m3 = movb[n * NHIST + 1],
              m4 = movb[n * NHIST + 0];

  const float* tb = trunk + ((size_t)n * C_TRUNK + c) * HW;
  float x0 = tb[i0], x1 = tb[i1], x2 = tb[i2], x3 = tb[i3], x4 = tb[i4];

  ushort* so = seq + (size_t)n * NHIST * C_TRUNK + c;
  so[0 * C_TRUNK] = f2bf(x0 * m0);   // seq[t] = feats[4-t]
  so[1 * C_TRUNK] = f2bf(x1 * m1);
  so[2 * C_TRUNK] = f2bf(x2 * m2);
  so[3 * C_TRUNK] = f2bf(x3 * m3);
  so[4 * C_TRUNK] = f2bf(x4 * m4);
}

// ---------------- Kernel C: G = seq @ w_ih^T + b_ih + b_hh  (bf16 MFMA) ------
// Unchanged from R4.
__global__ __launch_bounds__(256) void gates_kernel(
    const ushort* __restrict__ seq,  // (5120, 384) bf16
    const float* __restrict__ w_ih,  // (512, 384) fp32
    const float* __restrict__ b_ih,  // (512)
    const float* __restrict__ b_hh,  // (512)
    float* __restrict__ G)           // (5120, 512) fp32
{
  __shared__ ushort As[64][40];
  __shared__ ushort Bs[64][40];
  const int tid  = threadIdx.x;
  const int wv   = tid >> 6;
  const int lane = tid & 63;
  const int m0 = blockIdx.y * 64;
  const int j0 = blockIdx.x * 64;
  const int row_l = tid >> 2;
  const int koff  = (tid & 3) * 8;

  float4v acc0 = {0.f,0.f,0.f,0.f};
  float4v acc1 = {0.f,0.f,0.f,0.f};
  float4v acc2 = {0.f,0.f,0.f,0.f};
  float4v acc3 = {0.f,0.f,0.f,0.f};

  const int fr = lane & 15;
  const int fk = (lane >> 4) * 8;

  for (int k0 = 0; k0 < C_TRUNK; k0 += 32) {
    *(short8v*)&As[row_l][koff] =
        *(const short8v*)(seq + (size_t)(m0 + row_l) * C_TRUNK + k0 + koff);
    const float* wp = w_ih + (size_t)(j0 + row_l) * C_TRUNK + k0 + koff;
    float4 w0 = *(const float4*)wp;
    float4 w1 = *(const float4*)(wp + 4);
    short8v bvec;
    bvec[0] = (short)f2bf(w0.x); bvec[1] = (short)f2bf(w0.y);
    bvec[2] = (short)f2bf(w0.z); bvec[3] = (short)f2bf(w0.w);
    bvec[4] = (short)f2bf(w1.x); bvec[5] = (short)f2bf(w1.y);
    bvec[6] = (short)f2bf(w1.z); bvec[7] = (short)f2bf(w1.w);
    *(short8v*)&Bs[row_l][koff] = bvec;
    __syncthreads();

    short8v af  = *(const short8v*)&As[wv * 16 + fr][fk];
    short8v bf0 = *(const short8v*)&Bs[ 0 + fr][fk];
    short8v bf1 = *(const short8v*)&Bs[16 + fr][fk];
    short8v bf2 = *(const short8v*)&Bs[32 + fr][fk];
    short8v bf3 = *(const short8v*)&Bs[48 + fr][fk];
    acc0 = __builtin_amdgcn_mfma_f32_16x16x32_bf16(af, bf0, acc0, 0, 0, 0);
    acc1 = __builtin_amdgcn_mfma_f32_16x16x32_bf16(af, bf1, acc1, 0, 0, 0);
    acc2 = __builtin_amdgcn_mfma_f32_16x16x32_bf16(af, bf2, acc2, 0, 0, 0);
    acc3 = __builtin_amdgcn_mfma_f32_16x16x32_bf16(af, bf3, acc3, 0, 0, 0);
    __syncthreads();
  }

  const int rbase = m0 + wv * 16 + (lane >> 4) * 4;
  #pragma unroll
  for (int j = 0; j < 4; ++j) {
    const float4v a = (j == 0) ? acc0 : (j == 1) ? acc1 : (j == 2) ? acc2 : acc3;
    const int cj = j0 + j * 16 + fr;
    const float bsum = b_ih[cj] + b_hh[cj];
    #pragma unroll
    for (int r = 0; r < 4; ++r)
      G[(size_t)(rbase + r) * NGATE + cj] = a[r] + bsum;
  }
}

// ---------------- Kernel D: recurrence + projection (G fully prefetched) -----
__global__ __launch_bounds__(512, 2) void lstm_kernel(
    const float* __restrict__ G,       // (1024, 5, 512)
    const float* __restrict__ w_hh,    // (512, 128)
    const float* __restrict__ w_proj,  // (384, 128)
    const float* __restrict__ b_proj,  // (384)
    float* __restrict__ out)           // (1024, 384)
{
  const int n0  = blockIdx.x * 4;
  const int tid = threadIdx.x;
  const int g   = tid >> 7;
  const int j   = tid & 127;

  __shared__ float hs[4][HID];
  __shared__ float glds[4][4][HID];

  // prefetch all 20 gate pre-activations (independent of recurrence)
  float gpre[NHIST][4];
  #pragma unroll
  for (int t = 0; t < NHIST; ++t)
    #pragma unroll
    for (int s = 0; s < 4; ++s)
      gpre[t][s] = G[((size_t)(n0 + s) * NHIST + t) * NGATE + tid];

  float4 wreg[32];
  #pragma unroll
  for (int k4 = 0; k4 < 32; ++k4)
    wreg[k4] = *(const float4*)(w_hh + (size_t)(g * HID + j) * HID + k4 * 4);

  hs[g][j] = 0.f;
  float c = 0.f;
  __syncthreads();

  #pragma unroll
  for (int t = 0; t < NHIST; ++t) {
    float a[4];
    #pragma unroll
    for (int s = 0; s < 4; ++s) a[s] = gpre[t][s];

    #pragma unroll
    for (int k4 = 0; k4 < 32; ++k4) {
      float4 w = wreg[k4];
      #pragma unroll
      for (int s = 0; s < 4; ++s) {
        float4 h = *(const float4*)&hs[s][k4 * 4];
        a[s] += w.x * h.x + w.y * h.y + w.z * h.z + w.w * h.w;
      }
    }
    #pragma unroll
    for (int s = 0; s < 4; ++s) glds[g][s][j] = a[s];
    __syncthreads();
    {
      float ig = glds[0][g][j];
      float fg = glds[1][g][j];
      float gg = glds[2][g][j];
      float og = glds[3][g][j];
      ig = 1.f / (1.f + __expf(-ig));
      fg = 1.f / (1.f + __expf(-fg));
      og = 1.f / (1.f + __expf(-og));
      c  = fg * c + ig * tanhf(gg);
      hs[g][j] = og * tanhf(c);
    }
    __syncthreads();
  }

  if (tid < C_TRUNK) {
    const int cc = tid;
    const float4* wp = (const float4*)(w_proj + (size_t)cc * HID);
    float b = b_proj[cc];
    float po[4] = {b, b, b, b};
    #pragma unroll 8
    for (int k4 = 0; k4 < 32; ++k4) {
      float4 w  = wp[k4];
      float4 h0 = *(const float4*)&hs[0][k4 * 4];
      float4 h1 = *(const float4*)&hs[1][k4 * 4];
      float4 h2 = *(const float4*)&hs[2][k4 * 4];
      float4 h3 = *(const float4*)&hs[3][k4 * 4];
      po[0] += w.x*h0.x + w.y*h0.y + w.z*h0.z + w.w*h0.w;
      po[1] += w.x*h1.x + w.y*h1.y + w.z*h1.z + w.w*h1.w;
      po[2] += w.x*h2.x + w.y*h2.y + w.z*h2.z + w.w*h2.w;
      po[3] += w.x*h3.x + w.y*h3.y + w.z*h3.z + w.w*h3.w;
    }
    #pragma unroll
    for (int s = 0; s < 4; ++s)
      out[(size_t)(n0 + s) * C_TRUNK + cc] = po[s];
  }
}

extern "C" void kernel_launch(void* const* d_in, const int* in_sizes, int n_in,
                              void* d_out, int out_size, void* d_ws, size_t ws_size,
                              hipStream_t stream) {
  const float* inp    = (const float*)d_in[0];
  const float* trunk  = (const float*)d_in[1];
  const float* w_ih   = (const float*)d_in[2];
  const float* w_hh   = (const float*)d_in[3];
  const float* b_ih   = (const float*)d_in[4];
  const float* b_hh   = (const float*)d_in[5];
  const float* w_proj = (const float*)d_in[6];
  const float* b_proj = (const float*)d_in[7];
  float* out = (float*)d_out;

  char* ws = (char*)d_ws;
  int*    idxb = (int*)ws;                                    // 1024*5 int
  float*  movb = (float*)(ws + 20480);                        // 1024*5 f32
  ushort* seq  = (ushort*)(ws + 40960);                       // 5120*384 bf16
  float*  G    = (float*)(ws + 40960 +
                  (size_t)N_SAMP * NHIST * C_TRUNK * sizeof(ushort));

  argmax_kernel<<<N_SAMP, 320, 0, stream>>>(inp, idxb, movb);
  gather_kernel<<<N_SAMP, 384, 0, stream>>>(trunk, idxb, movb, seq);
  gates_kernel<<<dim3(NGATE / 64, (N_SAMP * NHIST) / 64), 256, 0, stream>>>(
      seq, w_ih, b_ih, b_hh, G);
  lstm_kernel<<<N_SAMP / 4, 512, 0, stream>>>(G, w_hh, w_proj, b_proj, out);
}